// Round 2
// baseline (673.150 us; speedup 1.0000x reference)
//
#include <hip/hip_runtime.h>
#include <hip/hip_bf16.h>

typedef unsigned short u16;
typedef unsigned int   u32;
typedef __attribute__((ext_vector_type(8))) short short8;   // 8 bf16 (MFMA A/B frag)
typedef __attribute__((ext_vector_type(4))) float f32x4;    // MFMA C/D frag

#define T_TOK 4096
#define HDIM  2048
#define NEXP  16
#define IDIM  1024
#define SIDIM 4096
#define RCAP  6144
#define NTIL  48

// ---- workspace layout (bytes) ----
#define O_WT      0u
#define O_EIDX    16384u
#define O_CNT     32768u
#define O_POS     32832u
#define O_PADOFF  32896u
#define O_TILEEXP 33024u
#define O_TOKROW  33280u
#define O_XBF     65536u                               // bf16[T][H]
#define O_XSC     (O_XBF  + 2u*T_TOK*HDIM)             // bf16[RCAP][H]
#define O_ACTS    (O_XSC  + 2u*RCAP*HDIM)              // bf16[T][SI]
#define O_ACTR    (O_ACTS + 2u*T_TOK*SIDIM)            // bf16[RCAP][I]
#define O_WSGT    (O_ACTR + 2u*RCAP*IDIM)              // bf16[SI][H]
#define O_WSUT    (O_WSGT + 2u*SIDIM*HDIM)
#define O_WSDT    (O_WSUT + 2u*SIDIM*HDIM)             // bf16[H][SI]
#define O_WGT     (O_WSDT + 2u*HDIM*SIDIM)             // bf16[E][I][H]
#define O_WUT     (O_WGT  + 2u*NEXP*IDIM*HDIM)
#define O_WDT     (O_WUT  + 2u*NEXP*IDIM*HDIM)         // bf16[E][H][I]
#define WS_SHARED_END (size_t)(O_WSDT + 2u*HDIM*SIDIM)
#define WS_FULL_END   (size_t)(O_WDT  + 2u*NEXP*HDIM*IDIM)

__device__ __forceinline__ u16 f2b(float f) {  // fp32 -> bf16, RNE
  u32 u = __float_as_uint(f);
  u = (u + 0x7FFFu + ((u >> 16) & 1u)) >> 16;
  return (u16)u;
}

// async global->LDS, 16B per lane; LDS dest must be lane-linear
#define GLDS16(g, l) __builtin_amdgcn_global_load_lds( \
    (const __attribute__((address_space(1))) void*)(g), \
    (__attribute__((address_space(3))) void*)(l), 16, 0, 0)

// ---------------- router: fp64 logits, top-1, sigmoid ----------------
__global__ __launch_bounds__(256) void router_k(
    const float* __restrict__ x, const float* __restrict__ rw,
    float* __restrict__ wt, int* __restrict__ eidx, int* __restrict__ cnt) {
  int w = threadIdx.x >> 6, l = threadIdx.x & 63;
  int t = blockIdx.x * 4 + w;
  double acc[NEXP];
#pragma unroll
  for (int e = 0; e < NEXP; ++e) acc[e] = 0.0;
  const float* xp = x + (size_t)t * HDIM;
  for (int hb = 0; hb < HDIM; hb += 256) {
    float4 xv = *(const float4*)(xp + hb + l * 4);
#pragma unroll
    for (int e = 0; e < NEXP; ++e) {
      float4 wv = *(const float4*)(rw + (size_t)e * HDIM + hb + l * 4);
      acc[e] += (double)xv.x * wv.x + (double)xv.y * wv.y
              + (double)xv.z * wv.z + (double)xv.w * wv.w;
    }
  }
#pragma unroll
  for (int e = 0; e < NEXP; ++e) {
    double v = acc[e];
#pragma unroll
    for (int off = 32; off; off >>= 1) v += __shfl_xor(v, off, 64);
    acc[e] = v;
  }
  if (l == 0) {
    double best = acc[0]; int be = 0;
#pragma unroll
    for (int e = 1; e < NEXP; ++e) if (acc[e] > best) { best = acc[e]; be = e; }
    wt[t] = 1.0f / (1.0f + __expf(-(float)best));
    eidx[t] = be;
    atomicAdd(&cnt[be], 1);
  }
}

__global__ void scan_k(const int* __restrict__ cnt, int* __restrict__ pad_off,
                       int* __restrict__ tile_exp, int* __restrict__ pos,
                       int* __restrict__ tok_row) {
  if (threadIdx.x == 0) {
    for (int i = 0; i < 64; ++i) tile_exp[i] = -1;
    int run = 0;
    for (int e = 0; e < NEXP; ++e) {
      pad_off[e] = run;
      int pc = ((cnt[e] + 127) >> 7) << 7;
      for (int tt = run >> 7; tt < (run + pc) >> 7; ++tt) tile_exp[tt] = e;
      run += pc;
      pos[e] = 0;
    }
    pad_off[NEXP] = run;
  }
  for (int i = threadIdx.x; i < RCAP; i += 256) tok_row[i] = -1;
}

__global__ void assign_k(const int* __restrict__ eidx, const int* __restrict__ pad_off,
                         int* __restrict__ pos, int* __restrict__ tok_row) {
  int t = blockIdx.x * 256 + threadIdx.x;
  if (t >= T_TOK) return;
  int e = eidx[t];
  int r = atomicAdd(&pos[e], 1);
  tok_row[pad_off[e] + r] = t;
}

// ---------------- x -> bf16 (xbf) and gathered+weighted x (xsc) ----------------
__global__ __launch_bounds__(256) void cvt_k(
    const float* __restrict__ x, const float* __restrict__ wt,
    const int* __restrict__ tok_row, u16* __restrict__ xbf, u16* __restrict__ xsc) {
  int row = blockIdx.x;
  int tid = threadIdx.x;
  if (row < T_TOK) {
    const float* src = x + (size_t)row * HDIM;
    u16* dst = xbf + (size_t)row * HDIM;
#pragma unroll
    for (int i = 0; i < 2; ++i) {
      int c = i * 1024 + tid * 4;
      float4 v = *(const float4*)(src + c);
      uint2 o;
      o.x = (u32)f2b(v.x) | ((u32)f2b(v.y) << 16);
      o.y = (u32)f2b(v.z) | ((u32)f2b(v.w) << 16);
      *(uint2*)(dst + c) = o;
    }
  } else {
    int g = row - T_TOK;
    u16* dst = xsc + (size_t)g * HDIM;
    int t = tok_row[g];
    if (t < 0) {
      uint2 z; z.x = 0u; z.y = 0u;
#pragma unroll
      for (int i = 0; i < 2; ++i) *(uint2*)(dst + i * 1024 + tid * 4) = z;
    } else {
      float s = wt[t];
      const float* src = x + (size_t)t * HDIM;
#pragma unroll
      for (int i = 0; i < 2; ++i) {
        int c = i * 1024 + tid * 4;
        float4 v = *(const float4*)(src + c);
        uint2 o;
        o.x = (u32)f2b(v.x * s) | ((u32)f2b(v.y * s) << 16);
        o.y = (u32)f2b(v.z * s) | ((u32)f2b(v.w * s) << 16);
        *(uint2*)(dst + c) = o;
      }
    }
  }
}

// ---------------- transpose-convert: fp32 [K][N] -> bf16 [N][K] ----------------
// block: 256 threads, tile 32(K) x 256(N). Coalesced fp32 reads per k-row;
// each thread writes one output row's 64B (32 bf16) -> full cachelines.
__global__ __launch_bounds__(256) void tconv_k(
    const float* __restrict__ src, u16* __restrict__ dst, int K, int N) {
  size_t boff = (size_t)blockIdx.z * (size_t)K * N;
  const float* sp = src + boff + (size_t)blockIdx.y * 32 * N + blockIdx.x * 256 + threadIdx.x;
  u32 h[16];
#pragma unroll
  for (int i = 0; i < 16; ++i) {
    float a = sp[(size_t)(2 * i) * N];
    float b = sp[(size_t)(2 * i + 1) * N];
    h[i] = (u32)f2b(a) | ((u32)f2b(b) << 16);
  }
  u16* dp = dst + boff + (size_t)(blockIdx.x * 256 + threadIdx.x) * K + blockIdx.y * 32;
  uint4* dq = (uint4*)dp;
  dq[0] = make_uint4(h[0], h[1], h[2], h[3]);
  dq[1] = make_uint4(h[4], h[5], h[6], h[7]);
  dq[2] = make_uint4(h[8], h[9], h[10], h[11]);
  dq[3] = make_uint4(h[12], h[13], h[14], h[15]);
}

// ================= GEMMs: BM=128, BK=64, 4 waves (2x2), mfma 16x16x32 bf16 =================
// A: bf16 [M][K] row-major, staged via global_load_lds with pre-swizzled source.
// B PRE : bf16 [N][K] row-major (pre-transposed weights), staged like A.
// B !PRE: fp32 [K][N], fused convert+transpose into LDS [n][72] (fallback).
// LDS chunk swizzle: LDS[r][chunk c] holds global chunk (c ^ (r&7)); reads XOR the same.

template<bool ROUTED, bool PRE>
__global__ __launch_bounds__(256) void gemm_gu(
    const u16* __restrict__ A, int lda,
    const void* __restrict__ Bg0, const void* __restrict__ Bu0,
    int ldb, size_t bstr, int K,
    u16* __restrict__ act, int ldact, const int* __restrict__ tile_exp) {
  __shared__ __align__(16) u16 As[128 * 64];
  __shared__ __align__(16) u16 Bgs[PRE ? 64 * 64 : 64 * 72];
  __shared__ __align__(16) u16 Bus[PRE ? 64 * 64 : 64 * 72];
  const int tid = threadIdx.x;
  const int w = tid >> 6, l = tid & 63;
  const int wm = w >> 1, wn = w & 1;
  const int m0 = blockIdx.y * 128, n0 = blockIdx.x * 64;
  int e = 0;
  if (ROUTED) { e = tile_exp[blockIdx.y]; if (e < 0) return; }
  const u16 *BgT = nullptr, *BuT = nullptr;
  const float *Bgf = nullptr, *Buf = nullptr;
  if constexpr (PRE) {
    size_t eo = ROUTED ? (size_t)e * bstr : 0;
    BgT = (const u16*)Bg0 + eo + (size_t)n0 * ldb;
    BuT = (const u16*)Bu0 + eo + (size_t)n0 * ldb;
  } else {
    size_t eo = ROUTED ? (size_t)e * bstr : 0;
    Bgf = (const float*)Bg0 + eo;
    Buf = (const float*)Bu0 + eo;
  }
  f32x4 accg[4][2], accu[4][2];
#pragma unroll
  for (int i = 0; i < 4; ++i)
#pragma unroll
    for (int j = 0; j < 2; ++j)
#pragma unroll
      for (int r = 0; r < 4; ++r) { accg[i][j][r] = 0.0f; accu[i][j][r] = 0.0f; }
  const u16* Ab = A + (size_t)m0 * lda;

  for (int k0 = 0; k0 < K; k0 += 64) {
    __syncthreads();
#pragma unroll
    for (int j = 0; j < 4; ++j) {           // stage A: 128x64 bf16, 16KB
      int c = j * 256 + tid, r = c >> 3, cc = c & 7;
      GLDS16(Ab + (size_t)r * lda + k0 + ((cc ^ (r & 7)) * 8), &As[c * 8]);
    }
    if constexpr (PRE) {
#pragma unroll
      for (int j = 0; j < 2; ++j) {         // stage Bg,Bu: 64x64 each
        int c = j * 256 + tid, r = c >> 3, cc = c & 7;
        int sc = (cc ^ (r & 7)) * 8;
        GLDS16(BgT + (size_t)r * ldb + k0 + sc, &Bgs[c * 8]);
        GLDS16(BuT + (size_t)r * ldb + k0 + sc, &Bus[c * 8]);
      }
    } else {
      const float* bp = Bgf + (size_t)(k0 + w * 16) * ldb + n0 + l;
      u16 h[16];
#pragma unroll
      for (int i = 0; i < 16; ++i) h[i] = f2b(bp[(size_t)i * ldb]);
#pragma unroll
      for (int j = 0; j < 4; ++j) {
        uint2 v; v.x = (u32)h[4*j] | ((u32)h[4*j+1] << 16);
        v.y = (u32)h[4*j+2] | ((u32)h[4*j+3] << 16);
        *(uint2*)&Bgs[l * 72 + w * 16 + j * 4] = v;
      }
      bp = Buf + (size_t)(k0 + w * 16) * ldb + n0 + l;
#pragma unroll
      for (int i = 0; i < 16; ++i) h[i] = f2b(bp[(size_t)i * ldb]);
#pragma unroll
      for (int j = 0; j < 4; ++j) {
        uint2 v; v.x = (u32)h[4*j] | ((u32)h[4*j+1] << 16);
        v.y = (u32)h[4*j+2] | ((u32)h[4*j+3] << 16);
        *(uint2*)&Bus[l * 72 + w * 16 + j * 4] = v;
      }
    }
    __syncthreads();
#pragma unroll
    for (int kh = 0; kh < 2; ++kh) {
      const int q = kh * 4 + (l >> 4);
      short8 af[4];
#pragma unroll
      for (int mf = 0; mf < 4; ++mf) {
        int r = wm * 64 + mf * 16 + (l & 15);
        af[mf] = *(const short8*)&As[r * 64 + ((q ^ (r & 7)) * 8)];
      }
      short8 bgf[2], buf2[2];
#pragma unroll
      for (int nf = 0; nf < 2; ++nf) {
        int n = wn * 32 + nf * 16 + (l & 15);
        if constexpr (PRE) {
          bgf[nf]  = *(const short8*)&Bgs[n * 64 + ((q ^ (n & 7)) * 8)];
          buf2[nf] = *(const short8*)&Bus[n * 64 + ((q ^ (n & 7)) * 8)];
        } else {
          bgf[nf]  = *(const short8*)&Bgs[n * 72 + q * 8];
          buf2[nf] = *(const short8*)&Bus[n * 72 + q * 8];
        }
      }
#pragma unroll
      for (int mf = 0; mf < 4; ++mf)
#pragma unroll
        for (int nf = 0; nf < 2; ++nf) {
          accg[mf][nf] = __builtin_amdgcn_mfma_f32_16x16x32_bf16(af[mf], bgf[nf],  accg[mf][nf], 0, 0, 0);
          accu[mf][nf] = __builtin_amdgcn_mfma_f32_16x16x32_bf16(af[mf], buf2[nf], accu[mf][nf], 0, 0, 0);
        }
    }
  }
#pragma unroll
  for (int mf = 0; mf < 4; ++mf)
#pragma unroll
    for (int nf = 0; nf < 2; ++nf) {
      int col = n0 + wn * 32 + nf * 16 + (l & 15);
#pragma unroll
      for (int r = 0; r < 4; ++r) {
        int row = m0 + wm * 64 + mf * 16 + (l >> 4) * 4 + r;
        float g = accg[mf][nf][r], u = accu[mf][nf][r];
        float s = g / (1.0f + __expf(-g));
        act[(size_t)row * ldact + col] = f2b(s * u);
      }
    }
}

template<bool ROUTED, bool PRE>
__global__ __launch_bounds__(256) void gemm_down(
    const u16* __restrict__ A, int lda,
    const void* __restrict__ B0, int ldb, size_t bstr, int K,
    float* __restrict__ out, int ldout,
    const int* __restrict__ tile_exp, const int* __restrict__ tok_row) {
  constexpr int BN  = PRE ? 128 : 64;
  constexpr int NFR = PRE ? 4 : 2;
  __shared__ __align__(16) u16 As[128 * 64];
  __shared__ __align__(16) u16 Bs[PRE ? 128 * 64 : 64 * 72];
  const int tid = threadIdx.x;
  const int w = tid >> 6, l = tid & 63;
  const int wm = w >> 1, wn = w & 1;
  const int m0 = blockIdx.y * 128, n0 = blockIdx.x * BN;
  int e = 0;
  if (ROUTED) { e = tile_exp[blockIdx.y]; if (e < 0) return; }
  const u16* BT = nullptr; const float* Bf = nullptr;
  if constexpr (PRE) {
    BT = (const u16*)B0 + (ROUTED ? (size_t)e * bstr : 0) + (size_t)n0 * ldb;
  } else {
    Bf = (const float*)B0 + (ROUTED ? (size_t)e * bstr : 0);
  }
  f32x4 acc[4][NFR];
#pragma unroll
  for (int i = 0; i < 4; ++i)
#pragma unroll
    for (int j = 0; j < NFR; ++j)
#pragma unroll
      for (int r = 0; r < 4; ++r) acc[i][j][r] = 0.0f;
  const u16* Ab = A + (size_t)m0 * lda;

  for (int k0 = 0; k0 < K; k0 += 64) {
    __syncthreads();
#pragma unroll
    for (int j = 0; j < 4; ++j) {
      int c = j * 256 + tid, r = c >> 3, cc = c & 7;
      GLDS16(Ab + (size_t)r * lda + k0 + ((cc ^ (r & 7)) * 8), &As[c * 8]);
    }
    if constexpr (PRE) {
#pragma unroll
      for (int j = 0; j < 4; ++j) {        // stage B: 128x64
        int c = j * 256 + tid, r = c >> 3, cc = c & 7;
        GLDS16(BT + (size_t)r * ldb + k0 + ((cc ^ (r & 7)) * 8), &Bs[c * 8]);
      }
    } else {
      const float* bp = Bf + (size_t)(k0 + w * 16) * ldb + n0 + l;
      u16 h[16];
#pragma unroll
      for (int i = 0; i < 16; ++i) h[i] = f2b(bp[(size_t)i * ldb]);
#pragma unroll
      for (int j = 0; j < 4; ++j) {
        uint2 v; v.x = (u32)h[4*j] | ((u32)h[4*j+1] << 16);
        v.y = (u32)h[4*j+2] | ((u32)h[4*j+3] << 16);
        *(uint2*)&Bs[l * 72 + w * 16 + j * 4] = v;
      }
    }
    __syncthreads();
#pragma unroll
    for (int kh = 0; kh < 2; ++kh) {
      const int q = kh * 4 + (l >> 4);
      short8 af[4];
#pragma unroll
      for (int mf = 0; mf < 4; ++mf) {
        int r = wm * 64 + mf * 16 + (l & 15);
        af[mf] = *(const short8*)&As[r * 64 + ((q ^ (r & 7)) * 8)];
      }
      short8 bf[NFR];
#pragma unroll
      for (int nf = 0; nf < NFR; ++nf) {
        int n = wn * (BN / 2) + nf * 16 + (l & 15);
        if constexpr (PRE) bf[nf] = *(const short8*)&Bs[n * 64 + ((q ^ (n & 7)) * 8)];
        else               bf[nf] = *(const short8*)&Bs[n * 72 + q * 8];
      }
#pragma unroll
      for (int mf = 0; mf < 4; ++mf)
#pragma unroll
        for (int nf = 0; nf < NFR; ++nf)
          acc[mf][nf] = __builtin_amdgcn_mfma_f32_16x16x32_bf16(af[mf], bf[nf], acc[mf][nf], 0, 0, 0);
    }
  }
#pragma unroll
  for (int mf = 0; mf < 4; ++mf)
#pragma unroll
    for (int nf = 0; nf < NFR; ++nf) {
      int col = n0 + wn * (BN / 2) + nf * 16 + (l & 15);
#pragma unroll
      for (int r = 0; r < 4; ++r) {
        int grow = m0 + wm * 64 + mf * 16 + (l >> 4) * 4 + r;
        float v = acc[mf][nf][r];
        if (ROUTED) {
          int t = tok_row[grow];
          if (t >= 0) out[(size_t)t * ldout + col] += v;
        } else {
          out[(size_t)grow * ldout + col] = v;
        }
      }
    }
}

extern "C" void kernel_launch(void* const* d_in, const int* in_sizes, int n_in,
                              void* d_out, int out_size, void* d_ws, size_t ws_size,
                              hipStream_t stream) {
  const float* x   = (const float*)d_in[0];
  const float* rw  = (const float*)d_in[1];
  const float* wg  = (const float*)d_in[2];
  const float* wu  = (const float*)d_in[3];
  const float* wd  = (const float*)d_in[4];
  const float* wsg = (const float*)d_in[5];
  const float* wsu = (const float*)d_in[6];
  const float* wsd = (const float*)d_in[7];
  float* out = (float*)d_out;
  char* ws = (char*)d_ws;

  float* wt     = (float*)(ws + O_WT);
  int* eidx     = (int*)(ws + O_EIDX);
  int* cnt      = (int*)(ws + O_CNT);
  int* pos      = (int*)(ws + O_POS);
  int* pad_off  = (int*)(ws + O_PADOFF);
  int* tile_exp = (int*)(ws + O_TILEEXP);
  int* tok_row  = (int*)(ws + O_TOKROW);
  u16* xbf      = (u16*)(ws + O_XBF);
  u16* xsc      = (u16*)(ws + O_XSC);
  u16* acts     = (u16*)(ws + O_ACTS);
  u16* actr     = (u16*)(ws + O_ACTR);
  u16* wsgT     = (u16*)(ws + O_WSGT);
  u16* wsuT     = (u16*)(ws + O_WSUT);
  u16* wsdT     = (u16*)(ws + O_WSDT);
  u16* wgT      = (u16*)(ws + O_WGT);
  u16* wuT      = (u16*)(ws + O_WUT);
  u16* wdT      = (u16*)(ws + O_WDT);

  const bool preS = ws_size >= WS_SHARED_END;   // pre-convert shared weights
  const bool preR = ws_size >= WS_FULL_END;     // pre-convert routed weights

  hipMemsetAsync(ws + O_CNT, 0, 128, stream);
  if (preS) {
    tconv_k<<<dim3(SIDIM / 256, HDIM / 32, 1), 256, 0, stream>>>(wsg, wsgT, HDIM, SIDIM);
    tconv_k<<<dim3(SIDIM / 256, HDIM / 32, 1), 256, 0, stream>>>(wsu, wsuT, HDIM, SIDIM);
    tconv_k<<<dim3(HDIM / 256, SIDIM / 32, 1), 256, 0, stream>>>(wsd, wsdT, SIDIM, HDIM);
  }
  if (preR) {
    tconv_k<<<dim3(IDIM / 256, HDIM / 32, NEXP), 256, 0, stream>>>(wg, wgT, HDIM, IDIM);
    tconv_k<<<dim3(IDIM / 256, HDIM / 32, NEXP), 256, 0, stream>>>(wu, wuT, HDIM, IDIM);
    tconv_k<<<dim3(HDIM / 256, IDIM / 32, NEXP), 256, 0, stream>>>(wd, wdT, IDIM, HDIM);
  }
  router_k<<<T_TOK / 4, 256, 0, stream>>>(x, rw, wt, eidx, cnt);
  scan_k<<<1, 256, 0, stream>>>(cnt, pad_off, tile_exp, pos, tok_row);
  assign_k<<<T_TOK / 256, 256, 0, stream>>>(eidx, pad_off, pos, tok_row);
  cvt_k<<<T_TOK + RCAP, 256, 0, stream>>>(x, wt, tok_row, xbf, xsc);

  if (preS)
    gemm_gu<false, true><<<dim3(SIDIM / 64, T_TOK / 128), 256, 0, stream>>>(
        xbf, HDIM, wsgT, wsuT, HDIM, 0, HDIM, acts, SIDIM, nullptr);
  else
    gemm_gu<false, false><<<dim3(SIDIM / 64, T_TOK / 128), 256, 0, stream>>>(
        xbf, HDIM, wsg, wsu, SIDIM, 0, HDIM, acts, SIDIM, nullptr);

  if (preR)
    gemm_gu<true, true><<<dim3(IDIM / 64, NTIL), 256, 0, stream>>>(
        xsc, HDIM, wgT, wuT, HDIM, (size_t)IDIM * HDIM, HDIM, actr, IDIM, tile_exp);
  else
    gemm_gu<true, false><<<dim3(IDIM / 64, NTIL), 256, 0, stream>>>(
        xsc, HDIM, wg, wu, IDIM, (size_t)HDIM * IDIM, HDIM, actr, IDIM, tile_exp);

  if (preS)
    gemm_down<false, true><<<dim3(HDIM / 128, T_TOK / 128), 256, 0, stream>>>(
        acts, SIDIM, wsdT, SIDIM, 0, SIDIM, out, HDIM, nullptr, nullptr);
  else
    gemm_down<false, false><<<dim3(HDIM / 64, T_TOK / 128), 256, 0, stream>>>(
        acts, SIDIM, wsd, HDIM, 0, SIDIM, out, HDIM, nullptr, nullptr);

  if (preR)
    gemm_down<true, true><<<dim3(HDIM / 128, NTIL), 256, 0, stream>>>(
        actr, IDIM, wdT, IDIM, (size_t)HDIM * IDIM, IDIM, out, HDIM, tile_exp, tok_row);
  else
    gemm_down<true, false><<<dim3(HDIM / 64, NTIL), 256, 0, stream>>>(
        actr, IDIM, wd, HDIM, (size_t)IDIM * HDIM, IDIM, out, HDIM, tile_exp, tok_row);
}

// Round 3
// 648.978 us; speedup vs baseline: 1.0372x; 1.0372x over previous
//
#include <hip/hip_runtime.h>
#include <hip/hip_bf16.h>

typedef unsigned short u16;
typedef unsigned int   u32;
typedef __attribute__((ext_vector_type(8))) short short8;   // 8 bf16 (MFMA A/B frag)
typedef __attribute__((ext_vector_type(4))) float f32x4;    // MFMA C/D frag

#define T_TOK 4096
#define HDIM  2048
#define NEXP  16
#define IDIM  1024
#define SIDIM 4096
#define RCAP  6144
#define NTIL  48

// ---- workspace layout (bytes) ----
#define O_WT      0u
#define O_EIDX    16384u
#define O_CNT     32768u
#define O_POS     32832u
#define O_PADOFF  32896u
#define O_TILEEXP 33024u
#define O_TOKROW  33280u
#define O_XBF     65536u                               // bf16[T][H]
#define O_XSC     (O_XBF  + 2u*T_TOK*HDIM)             // bf16[RCAP][H]
#define O_ACTS    (O_XSC  + 2u*RCAP*HDIM)              // bf16[T][SI]
#define O_ACTR    (O_ACTS + 2u*T_TOK*SIDIM)            // bf16[RCAP][I]
#define O_WSGT    (O_ACTR + 2u*RCAP*IDIM)              // bf16[SI][H]
#define O_WSUT    (O_WSGT + 2u*SIDIM*HDIM)
#define O_WSDT    (O_WSUT + 2u*SIDIM*HDIM)             // bf16[H][SI]
#define O_WGT     (O_WSDT + 2u*HDIM*SIDIM)             // bf16[E][I][H]
#define O_WUT     (O_WGT  + 2u*NEXP*IDIM*HDIM)
#define O_WDT     (O_WUT  + 2u*NEXP*IDIM*HDIM)         // bf16[E][H][I]

__device__ __forceinline__ u16 f2b(float f) {  // fp32 -> bf16, RNE
  u32 u = __float_as_uint(f);
  u = (u + 0x7FFFu + ((u >> 16) & 1u)) >> 16;
  return (u16)u;
}

#define GLDS16(g, l) __builtin_amdgcn_global_load_lds( \
    (const __attribute__((address_space(1))) void*)(g), \
    (__attribute__((address_space(3))) void*)(l), 16, 0, 0)
#define BARX() __builtin_amdgcn_s_barrier()
#define SETPRIO(x) __builtin_amdgcn_s_setprio(x)
#define WAITVM(n) asm volatile("s_waitcnt vmcnt(" #n ")" ::: "memory")

// ---------------- router: fp64 logits, top-1, sigmoid ----------------
__global__ __launch_bounds__(256) void router_k(
    const float* __restrict__ x, const float* __restrict__ rw,
    float* __restrict__ wt, int* __restrict__ eidx, int* __restrict__ cnt) {
  int w = threadIdx.x >> 6, l = threadIdx.x & 63;
  int t = blockIdx.x * 4 + w;
  double acc[NEXP];
#pragma unroll
  for (int e = 0; e < NEXP; ++e) acc[e] = 0.0;
  const float* xp = x + (size_t)t * HDIM;
  for (int hb = 0; hb < HDIM; hb += 256) {
    float4 xv = *(const float4*)(xp + hb + l * 4);
#pragma unroll
    for (int e = 0; e < NEXP; ++e) {
      float4 wv = *(const float4*)(rw + (size_t)e * HDIM + hb + l * 4);
      acc[e] += (double)xv.x * wv.x + (double)xv.y * wv.y
              + (double)xv.z * wv.z + (double)xv.w * wv.w;
    }
  }
#pragma unroll
  for (int e = 0; e < NEXP; ++e) {
    double v = acc[e];
#pragma unroll
    for (int off = 32; off; off >>= 1) v += __shfl_xor(v, off, 64);
    acc[e] = v;
  }
  if (l == 0) {
    double best = acc[0]; int be = 0;
#pragma unroll
    for (int e = 1; e < NEXP; ++e) if (acc[e] > best) { best = acc[e]; be = e; }
    wt[t] = 1.0f / (1.0f + __expf(-(float)best));
    eidx[t] = be;
    atomicAdd(&cnt[be], 1);
  }
}

__global__ void scan_k(const int* __restrict__ cnt, int* __restrict__ pad_off,
                       int* __restrict__ tile_exp, int* __restrict__ pos,
                       int* __restrict__ tok_row) {
  if (threadIdx.x == 0) {
    for (int i = 0; i < 64; ++i) tile_exp[i] = -1;
    int run = 0;
    for (int e = 0; e < NEXP; ++e) {
      pad_off[e] = run;
      int pc = ((cnt[e] + 127) >> 7) << 7;
      for (int tt = run >> 7; tt < (run + pc) >> 7; ++tt) tile_exp[tt] = e;
      run += pc;
      pos[e] = 0;
    }
    pad_off[NEXP] = run;
  }
  for (int i = threadIdx.x; i < RCAP; i += 256) tok_row[i] = -1;
}

__global__ void assign_k(const int* __restrict__ eidx, const int* __restrict__ pad_off,
                         int* __restrict__ pos, int* __restrict__ tok_row) {
  int t = blockIdx.x * 256 + threadIdx.x;
  if (t >= T_TOK) return;
  int e = eidx[t];
  int r = atomicAdd(&pos[e], 1);
  tok_row[pad_off[e] + r] = t;
}

// ---------------- x -> bf16 (xbf) and gathered+weighted x (xsc) ----------------
__global__ __launch_bounds__(256) void cvt_k(
    const float* __restrict__ x, const float* __restrict__ wt,
    const int* __restrict__ tok_row, u16* __restrict__ xbf, u16* __restrict__ xsc) {
  int row = blockIdx.x;
  int tid = threadIdx.x;
  if (row < T_TOK) {
    const float* src = x + (size_t)row * HDIM;
    u16* dst = xbf + (size_t)row * HDIM;
#pragma unroll
    for (int i = 0; i < 2; ++i) {
      int c = i * 1024 + tid * 4;
      float4 v = *(const float4*)(src + c);
      uint2 o;
      o.x = (u32)f2b(v.x) | ((u32)f2b(v.y) << 16);
      o.y = (u32)f2b(v.z) | ((u32)f2b(v.w) << 16);
      *(uint2*)(dst + c) = o;
    }
  } else {
    int g = row - T_TOK;
    u16* dst = xsc + (size_t)g * HDIM;
    int t = tok_row[g];
    if (t < 0) {
      uint2 z; z.x = 0u; z.y = 0u;
#pragma unroll
      for (int i = 0; i < 2; ++i) *(uint2*)(dst + i * 1024 + tid * 4) = z;
    } else {
      float s = wt[t];
      const float* src = x + (size_t)t * HDIM;
#pragma unroll
      for (int i = 0; i < 2; ++i) {
        int c = i * 1024 + tid * 4;
        float4 v = *(const float4*)(src + c);
        uint2 o;
        o.x = (u32)f2b(v.x * s) | ((u32)f2b(v.y * s) << 16);
        o.y = (u32)f2b(v.z * s) | ((u32)f2b(v.w * s) << 16);
        *(uint2*)(dst + c) = o;
      }
    }
  }
}

// ---------------- transpose-convert via LDS: fp32 [K][N] -> bf16 [N][K] ----------------
// 64x64 tile, coalesced reads and coalesced 128B-line writes.
__global__ __launch_bounds__(256) void tconv_k(
    const float* __restrict__ src, u16* __restrict__ dst, int K, int N) {
  __shared__ u32 lt[64][36];   // [n][k-pair], stride 36 keeps b128 alignment + spread
  size_t boff = (size_t)blockIdx.z * (size_t)K * N;
  const int n0 = blockIdx.x * 64, k0 = blockIdx.y * 64;
  const int l = threadIdx.x & 63, w = threadIdx.x >> 6;   // w 0..3 -> 16 k-rows each
  const float* sp = src + boff + (size_t)(k0 + w * 16) * N + n0 + l;
  u32 p[8];
#pragma unroll
  for (int i = 0; i < 8; ++i) {
    float a = sp[(size_t)(2 * i) * N];
    float b = sp[(size_t)(2 * i + 1) * N];
    p[i] = (u32)f2b(a) | ((u32)f2b(b) << 16);
  }
  *(uint4*)&lt[l][w * 8 + 0] = make_uint4(p[0], p[1], p[2], p[3]);
  *(uint4*)&lt[l][w * 8 + 4] = make_uint4(p[4], p[5], p[6], p[7]);
  __syncthreads();
  const int c = threadIdx.x & 7, n2 = threadIdx.x >> 3;   // n2 0..31, c = 16B chunk
#pragma unroll
  for (int rnd = 0; rnd < 2; ++rnd) {
    int n = n2 + rnd * 32;
    uint4 v = *(const uint4*)&lt[n][c * 4];
    *(uint4*)(dst + boff + (size_t)(n0 + n) * K + k0 + c * 8) = v;
  }
}

// ================= 8-phase 256-row shared GEMMs (T2+T3+T4+T5) =================
// LDS half-slots: [buf][khalf] of [256 rows][32 k] bf16 (A), B same (gu) / 128 rows (down).
// chunk swizzle: LDS[r][cpos] holds global chunk cpos^(r&3); read chunk (l>>4)^(r&3).

__device__ __forceinline__ void mmA(f32x4 (&acc)[4][8], const short8 (&af)[4],
                                    const short8 (&bfr)[4], int h) {
  SETPRIO(1);
#pragma unroll
  for (int mf = 0; mf < 4; ++mf)
#pragma unroll
    for (int nf = 0; nf < 4; ++nf)
      acc[mf][h * 4 + nf] = __builtin_amdgcn_mfma_f32_16x16x32_bf16(
          af[mf], bfr[nf], acc[mf][h * 4 + nf], 0, 0, 0);
  SETPRIO(0);
}
__device__ __forceinline__ void mmD(f32x4 (&acc)[4][4], const short8 (&af)[4],
                                    const short8 (&bfr)[2], int h) {
  SETPRIO(1);
#pragma unroll
  for (int mf = 0; mf < 4; ++mf)
#pragma unroll
    for (int nf = 0; nf < 2; ++nf)
      acc[mf][h * 2 + nf] = __builtin_amdgcn_mfma_f32_16x16x32_bf16(
          af[mf], bfr[nf], acc[mf][h * 2 + nf], 0, 0, 0);
  SETPRIO(0);
}

// ---- shared gate/up: A=xbf[4096][2048], B=wsgT/wsuT[4096][2048] interleaved, out act bf16
__global__ __launch_bounds__(512, 2) void gu_sh8(
    const u16* __restrict__ A, const u16* __restrict__ Bg, const u16* __restrict__ Bu,
    u16* __restrict__ act) {
  extern __shared__ u16 sm[];
  u16* As  = sm;            // [2][2][8192]
  u16* Bsm = sm + 32768;    // [2][2][8192]
  const int bid = blockIdx.x;
  const int swz = (bid & 7) * 64 + (bid >> 3);          // XCD swizzle, 512 blocks
  const int bx = swz & 31, by = swz >> 5;
  const int m0 = by * 256, c0 = bx * 128;
  const int tid = threadIdx.x, l = tid & 63, wid = tid >> 6;
  const int wm = wid >> 1, wn = wid & 1;

  // staging source (pre-swizzled global chunks, lane-linear LDS dest)
  const int cpos = tid & 3, rr = tid >> 2;              // rr 0..127
  const int gc = (cpos ^ (rr & 3)) * 8;
  const u16* aS0 = A + (size_t)(m0 + rr) * HDIM + gc;
  const u16* aS1 = A + (size_t)(m0 + 128 + rr) * HDIM + gc;
  const int mat = (rr >> 6) & 1;                        // v and v+128 share mat
  const u16* bbase = mat ? Bu : Bg;
  const u16* bS0 = bbase + (size_t)(c0 + (rr & 63)) * HDIM + gc;
  const u16* bS1 = bbase + (size_t)(c0 + 64 + (rr & 63)) * HDIM + gc;
  const int ld0 = tid * 8, ld1 = (512 + tid) * 8;

#define STA_G(bb, kh, koff) do { \
    GLDS16(aS0 + (koff) + (kh) * 32, As + ((bb) * 2 + (kh)) * 8192 + ld0); \
    GLDS16(aS1 + (koff) + (kh) * 32, As + ((bb) * 2 + (kh)) * 8192 + ld1); } while (0)
#define STB_G(bb, kh, koff) do { \
    GLDS16(bS0 + (koff) + (kh) * 32, Bsm + ((bb) * 2 + (kh)) * 8192 + ld0); \
    GLDS16(bS1 + (koff) + (kh) * 32, Bsm + ((bb) * 2 + (kh)) * 8192 + ld1); } while (0)

  const int fch = ((l >> 4) ^ (l & 3)) * 8;
  int aoff[4], boff[8];
#pragma unroll
  for (int mf = 0; mf < 4; ++mf) aoff[mf] = (wm * 64 + mf * 16 + (l & 15)) * 32 + fch;
#pragma unroll
  for (int i = 0; i < 8; ++i) {
    int v = wn * 128 + (i >> 2) * 64 + (i & 3) * 16 + (l & 15);
    boff[i] = v * 32 + fch;
  }
#define LDA_G(bb, kh) do { const u16* s_ = As + ((bb) * 2 + (kh)) * 8192; \
    af[0] = *(const short8*)(s_ + aoff[0]); af[1] = *(const short8*)(s_ + aoff[1]); \
    af[2] = *(const short8*)(s_ + aoff[2]); af[3] = *(const short8*)(s_ + aoff[3]); } while (0)
#define LDB_G(bb, kh, h) do { const u16* s_ = Bsm + ((bb) * 2 + (kh)) * 8192; \
    bfr[0] = *(const short8*)(s_ + boff[(h) * 4 + 0]); bfr[1] = *(const short8*)(s_ + boff[(h) * 4 + 1]); \
    bfr[2] = *(const short8*)(s_ + boff[(h) * 4 + 2]); bfr[3] = *(const short8*)(s_ + boff[(h) * 4 + 3]); } while (0)

  f32x4 acc[4][8];
#pragma unroll
  for (int i = 0; i < 4; ++i)
#pragma unroll
    for (int j = 0; j < 8; ++j)
#pragma unroll
      for (int r = 0; r < 4; ++r) acc[i][j][r] = 0.0f;
  short8 af[4], bfr[4];

  STA_G(0, 0, 0); STB_G(0, 0, 0); STA_G(0, 1, 0); STB_G(0, 1, 0);
  WAITVM(0); BARX();
  const int NT = HDIM / 64;                              // 32
  for (int t = 0; t < NT - 1; ++t) {
    const int b = t & 1, nb = b ^ 1, kn = (t + 1) * 64;
    LDA_G(b, 0); LDB_G(b, 0, 0); STA_G(nb, 0, kn); BARX(); mmA(acc, af, bfr, 0); BARX();
    LDB_G(b, 0, 1);              STB_G(nb, 0, kn); BARX(); mmA(acc, af, bfr, 1); WAITVM(4); BARX();
    LDA_G(b, 1); LDB_G(b, 1, 0); STA_G(nb, 1, kn); BARX(); mmA(acc, af, bfr, 0); BARX();
    LDB_G(b, 1, 1);              STB_G(nb, 1, kn); BARX(); mmA(acc, af, bfr, 1); WAITVM(4); BARX();
  }
  { const int b = (NT - 1) & 1;
    LDA_G(b, 0); LDB_G(b, 0, 0); BARX(); mmA(acc, af, bfr, 0); BARX();
    LDB_G(b, 0, 1);              BARX(); mmA(acc, af, bfr, 1); WAITVM(0); BARX();
    LDA_G(b, 1); LDB_G(b, 1, 0); BARX(); mmA(acc, af, bfr, 0); BARX();
    LDB_G(b, 1, 1);              mmA(acc, af, bfr, 1);
  }
  // epilogue: silu(gate)*up -> bf16 act
#pragma unroll
  for (int mf = 0; mf < 4; ++mf)
#pragma unroll
    for (int nf = 0; nf < 4; ++nf) {
      int col = c0 + wn * 64 + nf * 16 + (l & 15);
      int rowb = m0 + wm * 64 + mf * 16 + (l >> 4) * 4;
#pragma unroll
      for (int r = 0; r < 4; ++r) {
        float g = acc[mf][nf][r], u = acc[mf][4 + nf][r];
        float s = g / (1.0f + __expf(-g));
        act[(size_t)(rowb + r) * SIDIM + col] = f2b(s * u);
      }
    }
#undef STA_G
#undef STB_G
#undef LDA_G
#undef LDB_G
}

// ---- shared down: A=acts[4096][4096], B=wsdT[2048][4096], out fp32 [4096][2048]
__global__ __launch_bounds__(512, 2) void dn_sh8(
    const u16* __restrict__ A, const u16* __restrict__ B, float* __restrict__ out) {
  extern __shared__ u16 sm[];
  u16* As  = sm;            // [2][2][8192]
  u16* Bsm = sm + 32768;    // [2][2][4096]
  const int bid = blockIdx.x;
  const int swz = (bid & 7) * 32 + (bid >> 3);          // 256 blocks
  const int bx = swz & 15, by = swz >> 4;
  const int m0 = by * 256, c0 = bx * 128;
  const int tid = threadIdx.x, l = tid & 63, wid = tid >> 6;
  const int wm = wid >> 1, wn = wid & 1;

  const int cpos = tid & 3, rr = tid >> 2;
  const int gc = (cpos ^ (rr & 3)) * 8;
  const u16* aS0 = A + (size_t)(m0 + rr) * SIDIM + gc;
  const u16* aS1 = A + (size_t)(m0 + 128 + rr) * SIDIM + gc;
  const u16* bS  = B + (size_t)(c0 + rr) * SIDIM + gc;
  const int ld0 = tid * 8, ld1 = (512 + tid) * 8;

#define STA_D(bb, kh, koff) do { \
    GLDS16(aS0 + (koff) + (kh) * 32, As + ((bb) * 2 + (kh)) * 8192 + ld0); \
    GLDS16(aS1 + (koff) + (kh) * 32, As + ((bb) * 2 + (kh)) * 8192 + ld1); } while (0)
#define STB_D(bb, kh, koff) \
    GLDS16(bS + (koff) + (kh) * 32, Bsm + ((bb) * 2 + (kh)) * 4096 + ld0)

  const int fch = ((l >> 4) ^ (l & 3)) * 8;
  int aoff[4], boff[4];
#pragma unroll
  for (int mf = 0; mf < 4; ++mf) aoff[mf] = (wm * 64 + mf * 16 + (l & 15)) * 32 + fch;
#pragma unroll
  for (int i = 0; i < 4; ++i) {
    int v = wn * 64 + (i >> 1) * 32 + (i & 1) * 16 + (l & 15);
    boff[i] = v * 32 + fch;
  }
#define LDA_D(bb, kh) do { const u16* s_ = As + ((bb) * 2 + (kh)) * 8192; \
    af[0] = *(const short8*)(s_ + aoff[0]); af[1] = *(const short8*)(s_ + aoff[1]); \
    af[2] = *(const short8*)(s_ + aoff[2]); af[3] = *(const short8*)(s_ + aoff[3]); } while (0)
#define LDB_D(bb, kh, h) do { const u16* s_ = Bsm + ((bb) * 2 + (kh)) * 4096; \
    bfr[0] = *(const short8*)(s_ + boff[(h) * 2 + 0]); \
    bfr[1] = *(const short8*)(s_ + boff[(h) * 2 + 1]); } while (0)

  f32x4 acc[4][4];
#pragma unroll
  for (int i = 0; i < 4; ++i)
#pragma unroll
    for (int j = 0; j < 4; ++j)
#pragma unroll
      for (int r = 0; r < 4; ++r) acc[i][j][r] = 0.0f;
  short8 af[4]; short8 bfr[2];

  STA_D(0, 0, 0); STB_D(0, 0, 0); STA_D(0, 1, 0); STB_D(0, 1, 0);
  WAITVM(0); BARX();
  const int NT = SIDIM / 64;                             // 64
  for (int t = 0; t < NT - 1; ++t) {
    const int b = t & 1, nb = b ^ 1, kn = (t + 1) * 64;
    LDA_D(b, 0); LDB_D(b, 0, 0); STA_D(nb, 0, kn); BARX(); mmD(acc, af, bfr, 0); BARX();
    LDB_D(b, 0, 1);              STB_D(nb, 0, kn); BARX(); mmD(acc, af, bfr, 1); WAITVM(3); BARX();
    LDA_D(b, 1); LDB_D(b, 1, 0); STA_D(nb, 1, kn); BARX(); mmD(acc, af, bfr, 0); BARX();
    LDB_D(b, 1, 1);              STB_D(nb, 1, kn); BARX(); mmD(acc, af, bfr, 1); WAITVM(3); BARX();
  }
  { const int b = (NT - 1) & 1;
    LDA_D(b, 0); LDB_D(b, 0, 0); BARX(); mmD(acc, af, bfr, 0); BARX();
    LDB_D(b, 0, 1);              BARX(); mmD(acc, af, bfr, 1); WAITVM(0); BARX();
    LDA_D(b, 1); LDB_D(b, 1, 0); BARX(); mmD(acc, af, bfr, 0); BARX();
    LDB_D(b, 1, 1);              mmD(acc, af, bfr, 1);
  }
#pragma unroll
  for (int mf = 0; mf < 4; ++mf)
#pragma unroll
    for (int nf = 0; nf < 4; ++nf) {
      int col = c0 + wn * 64 + (nf >> 1) * 32 + (nf & 1) * 16 + (l & 15);
      int rowb = m0 + wm * 64 + mf * 16 + (l >> 4) * 4;
#pragma unroll
      for (int r = 0; r < 4; ++r)
        out[(size_t)(rowb + r) * HDIM + col] = acc[mf][nf][r];
    }
#undef STA_D
#undef STB_D
#undef LDA_D
#undef LDB_D
}

// ================= routed GEMMs (proven round-2 structure, PRE bf16 weights) =================
__global__ __launch_bounds__(256) void gu_r(
    const u16* __restrict__ A, const u16* __restrict__ BgT, const u16* __restrict__ BuT,
    u16* __restrict__ act, const int* __restrict__ tile_exp) {
  __shared__ __align__(16) u16 As[128 * 64];
  __shared__ __align__(16) u16 Bgs[64 * 64];
  __shared__ __align__(16) u16 Bus[64 * 64];
  const int tid = threadIdx.x;
  const int l = tid & 63, w = tid >> 6;
  const int wm = w >> 1, wn = w & 1;
  const int m0 = blockIdx.y * 128, n0 = blockIdx.x * 64;
  int e = tile_exp[blockIdx.y];
  if (e < 0) return;
  size_t eo = (size_t)e * IDIM * HDIM;
  const u16* Bg = BgT + eo + (size_t)n0 * HDIM;
  const u16* Bu = BuT + eo + (size_t)n0 * HDIM;
  f32x4 accg[4][2], accu[4][2];
#pragma unroll
  for (int i = 0; i < 4; ++i)
#pragma unroll
    for (int j = 0; j < 2; ++j)
#pragma unroll
      for (int r = 0; r < 4; ++r) { accg[i][j][r] = 0.0f; accu[i][j][r] = 0.0f; }
  const u16* Ab = A + (size_t)m0 * HDIM;

  for (int k0 = 0; k0 < HDIM; k0 += 64) {
    __syncthreads();
#pragma unroll
    for (int j = 0; j < 4; ++j) {
      int c = j * 256 + tid, r = c >> 3, cc = c & 7;
      GLDS16(Ab + (size_t)r * HDIM + k0 + ((cc ^ (r & 7)) * 8), &As[c * 8]);
    }
#pragma unroll
    for (int j = 0; j < 2; ++j) {
      int c = j * 256 + tid, r = c >> 3, cc = c & 7;
      int sc = (cc ^ (r & 7)) * 8;
      GLDS16(Bg + (size_t)r * HDIM + k0 + sc, &Bgs[c * 8]);
      GLDS16(Bu + (size_t)r * HDIM + k0 + sc, &Bus[c * 8]);
    }
    __syncthreads();
#pragma unroll
    for (int kh = 0; kh < 2; ++kh) {
      const int q = kh * 4 + (l >> 4);
      short8 af[4];
#pragma unroll
      for (int mf = 0; mf < 4; ++mf) {
        int r = wm * 64 + mf * 16 + (l & 15);
        af[mf] = *(const short8*)&As[r * 64 + ((q ^ (r & 7)) * 8)];
      }
      short8 bgf[2], buf2[2];
#pragma unroll
      for (int nf = 0; nf < 2; ++nf) {
        int n = wn * 32 + nf * 16 + (l & 15);
        bgf[nf]  = *(const short8*)&Bgs[n * 64 + ((q ^ (n & 7)) * 8)];
        buf2[nf] = *(const short8*)&Bus[n * 64 + ((q ^ (n & 7)) * 8)];
      }
#pragma unroll
      for (int mf = 0; mf < 4; ++mf)
#pragma unroll
        for (int nf = 0; nf < 2; ++nf) {
          accg[mf][nf] = __builtin_amdgcn_mfma_f32_16x16x32_bf16(af[mf], bgf[nf],  accg[mf][nf], 0, 0, 0);
          accu[mf][nf] = __builtin_amdgcn_mfma_f32_16x16x32_bf16(af[mf], buf2[nf], accu[mf][nf], 0, 0, 0);
        }
    }
  }
#pragma unroll
  for (int mf = 0; mf < 4; ++mf)
#pragma unroll
    for (int nf = 0; nf < 2; ++nf) {
      int col = n0 + wn * 32 + nf * 16 + (l & 15);
#pragma unroll
      for (int r = 0; r < 4; ++r) {
        int row = m0 + wm * 64 + mf * 16 + (l >> 4) * 4 + r;
        float g = accg[mf][nf][r], u = accu[mf][nf][r];
        float s = g / (1.0f + __expf(-g));
        act[(size_t)row * IDIM + col] = f2b(s * u);
      }
    }
}

__global__ __launch_bounds__(256) void dn_r(
    const u16* __restrict__ A, const u16* __restrict__ BT, float* __restrict__ out,
    const int* __restrict__ tile_exp, const int* __restrict__ tok_row) {
  __shared__ __align__(16) u16 As[128 * 64];
  __shared__ __align__(16) u16 Bs[128 * 64];
  const int tid = threadIdx.x;
  const int l = tid & 63, w = tid >> 6;
  const int wm = w >> 1, wn = w & 1;
  const int m0 = blockIdx.y * 128, n0 = blockIdx.x * 128;
  int e = tile_exp[blockIdx.y];
  if (e < 0) return;
  const u16* B = BT + (size_t)e * HDIM * IDIM + (size_t)n0 * IDIM;
  f32x4 acc[4][4];
#pragma unroll
  for (int i = 0; i < 4; ++i)
#pragma unroll
    for (int j = 0; j < 4; ++j)
#pragma unroll
      for (int r = 0; r < 4; ++r) acc[i][j][r] = 0.0f;
  const u16* Ab = A + (size_t)m0 * IDIM;

  for (int k0 = 0; k0 < IDIM; k0 += 64) {
    __syncthreads();
#pragma unroll
    for (int j = 0; j < 4; ++j) {
      int c = j * 256 + tid, r = c >> 3, cc = c & 7;
      GLDS16(Ab + (size_t)r * IDIM + k0 + ((cc ^ (r & 7)) * 8), &As[c * 8]);
    }
#pragma unroll
    for (int j = 0; j < 4; ++j) {
      int c = j * 256 + tid, r = c >> 3, cc = c & 7;
      GLDS16(B + (size_t)r * IDIM + k0 + ((cc ^ (r & 7)) * 8), &Bs[c * 8]);
    }
    __syncthreads();
#pragma unroll
    for (int kh = 0; kh < 2; ++kh) {
      const int q = kh * 4 + (l >> 4);
      short8 af[4];
#pragma unroll
      for (int mf = 0; mf < 4; ++mf) {
        int r = wm * 64 + mf * 16 + (l & 15);
        af[mf] = *(const short8*)&As[r * 64 + ((q ^ (r & 7)) * 8)];
      }
      short8 bf[4];
#pragma unroll
      for (int nf = 0; nf < 4; ++nf) {
        int n = wn * 64 + nf * 16 + (l & 15);
        bf[nf] = *(const short8*)&Bs[n * 64 + ((q ^ (n & 7)) * 8)];
      }
#pragma unroll
      for (int mf = 0; mf < 4; ++mf)
#pragma unroll
        for (int nf = 0; nf < 4; ++nf)
          acc[mf][nf] = __builtin_amdgcn_mfma_f32_16x16x32_bf16(af[mf], bf[nf], acc[mf][nf], 0, 0, 0);
    }
  }
#pragma unroll
  for (int mf = 0; mf < 4; ++mf)
#pragma unroll
    for (int nf = 0; nf < 4; ++nf) {
      int col = n0 + wn * 64 + nf * 16 + (l & 15);
#pragma unroll
      for (int r = 0; r < 4; ++r) {
        int grow = m0 + wm * 64 + mf * 16 + (l >> 4) * 4 + r;
        int t = tok_row[grow];
        if (t >= 0) out[(size_t)t * HDIM + col] += acc[mf][nf][r];
      }
    }
}

extern "C" void kernel_launch(void* const* d_in, const int* in_sizes, int n_in,
                              void* d_out, int out_size, void* d_ws, size_t ws_size,
                              hipStream_t stream) {
  const float* x   = (const float*)d_in[0];
  const float* rw  = (const float*)d_in[1];
  const float* wg  = (const float*)d_in[2];
  const float* wu  = (const float*)d_in[3];
  const float* wd  = (const float*)d_in[4];
  const float* wsg = (const float*)d_in[5];
  const float* wsu = (const float*)d_in[6];
  const float* wsd = (const float*)d_in[7];
  float* out = (float*)d_out;
  char* ws = (char*)d_ws;

  float* wt     = (float*)(ws + O_WT);
  int* eidx     = (int*)(ws + O_EIDX);
  int* cnt      = (int*)(ws + O_CNT);
  int* pos      = (int*)(ws + O_POS);
  int* pad_off  = (int*)(ws + O_PADOFF);
  int* tile_exp = (int*)(ws + O_TILEEXP);
  int* tok_row  = (int*)(ws + O_TOKROW);
  u16* xbf      = (u16*)(ws + O_XBF);
  u16* xsc      = (u16*)(ws + O_XSC);
  u16* acts     = (u16*)(ws + O_ACTS);
  u16* actr     = (u16*)(ws + O_ACTR);
  u16* wsgT     = (u16*)(ws + O_WSGT);
  u16* wsuT     = (u16*)(ws + O_WSUT);
  u16* wsdT     = (u16*)(ws + O_WSDT);
  u16* wgT      = (u16*)(ws + O_WGT);
  u16* wuT      = (u16*)(ws + O_WUT);
  u16* wdT      = (u16*)(ws + O_WDT);

  hipMemsetAsync(ws + O_CNT, 0, 128, stream);
  // weight transpose-convert (LDS-tiled, coalesced both sides)
  tconv_k<<<dim3(SIDIM / 64, HDIM / 64, 1), 256, 0, stream>>>(wsg, wsgT, HDIM, SIDIM);
  tconv_k<<<dim3(SIDIM / 64, HDIM / 64, 1), 256, 0, stream>>>(wsu, wsuT, HDIM, SIDIM);
  tconv_k<<<dim3(HDIM / 64, SIDIM / 64, 1), 256, 0, stream>>>(wsd, wsdT, SIDIM, HDIM);
  tconv_k<<<dim3(IDIM / 64, HDIM / 64, NEXP), 256, 0, stream>>>(wg, wgT, HDIM, IDIM);
  tconv_k<<<dim3(IDIM / 64, HDIM / 64, NEXP), 256, 0, stream>>>(wu, wuT, HDIM, IDIM);
  tconv_k<<<dim3(HDIM / 64, IDIM / 64, NEXP), 256, 0, stream>>>(wd, wdT, IDIM, HDIM);

  router_k<<<T_TOK / 4, 256, 0, stream>>>(x, rw, wt, eidx, cnt);
  scan_k<<<1, 256, 0, stream>>>(cnt, pad_off, tile_exp, pos, tok_row);
  assign_k<<<T_TOK / 256, 256, 0, stream>>>(eidx, pad_off, pos, tok_row);
  cvt_k<<<T_TOK + RCAP, 256, 0, stream>>>(x, wt, tok_row, xbf, xsc);

  static bool attr_set = false;
  if (!attr_set) {
    hipFuncSetAttribute((const void*)gu_sh8, hipFuncAttributeMaxDynamicSharedMemorySize, 131072);
    hipFuncSetAttribute((const void*)dn_sh8, hipFuncAttributeMaxDynamicSharedMemorySize, 98304);
    attr_set = true;
  }
  gu_sh8<<<512, 512, 131072, stream>>>(xbf, wsgT, wsuT, acts);
  gu_r<<<dim3(IDIM / 64, NTIL), 256, 0, stream>>>(xsc, wgT, wuT, actr, tile_exp);
  dn_sh8<<<256, 512, 98304, stream>>>(acts, wsdT, out);
  dn_r<<<dim3(HDIM / 128, NTIL), 256, 0, stream>>>(actr, wdT, out, tile_exp, tok_row);
}